// Round 1
// baseline (274.935 us; speedup 1.0000x reference)
//
#include <hip/hip_runtime.h>

// out[..., m] = b[..., m] + ALPHA * b[..., m+1]  (m < 39);  out[..., 39] = b[..., 39]
// b: (16, 65536, 40) float32, flat n = 41,943,040 (divisible by 4; row = 40 = 10 float4s)

static constexpr float kAlpha = 0.42f;

__global__ void __launch_bounds__(256)
b2mc_kernel(const float* __restrict__ b, float* __restrict__ out, int n4) {
    const float4* __restrict__ b4 = reinterpret_cast<const float4*>(b);
    float4* __restrict__ o4 = reinterpret_cast<float4*>(out);
    const int stride = gridDim.x * blockDim.x;
    for (int i = blockIdx.x * blockDim.x + threadIdx.x; i < n4; i += stride) {
        float4 v = b4[i];

        // Shifted neighbor for .w is the next float4's .x. Consecutive lanes hold
        // consecutive float4 indices, so grab it cross-lane; only lane 63 needs a
        // real load (hits L1/L2 — neighbor wave loads that line anyway).
        float nxt = __shfl_down(v.x, 1);
        const bool rowend = (i % 10) == 9;   // element (4i+3) is m==39 of its row
        if (((threadIdx.x & 63) == 63) && !rowend) {
            nxt = b[4 * i + 4];              // in-bounds: rowend covers the array end
        }
        if (rowend) nxt = 0.0f;              // last coefficient passes through

        float4 r;
        r.x = fmaf(kAlpha, v.y, v.x);
        r.y = fmaf(kAlpha, v.z, v.y);
        r.z = fmaf(kAlpha, v.w, v.z);
        r.w = fmaf(kAlpha, nxt, v.w);
        o4[i] = r;
    }
}

extern "C" void kernel_launch(void* const* d_in, const int* in_sizes, int n_in,
                              void* d_out, int out_size, void* d_ws, size_t ws_size,
                              hipStream_t stream) {
    const float* b = (const float*)d_in[0];
    float* out = (float*)d_out;
    const int n = in_sizes[0];       // 41,943,040
    const int n4 = n / 4;            // 10,485,760 float4s
    const int block = 256;
    int grid = 2048;                 // memory-bound: cap + grid-stride (G11)
    const int need = (n4 + block - 1) / block;
    if (need < grid) grid = need;
    b2mc_kernel<<<grid, block, 0, stream>>>(b, out, n4);
}